// Round 1
// baseline (1191.145 us; speedup 1.0000x reference)
//
#include <hip/hip_runtime.h>
#include <math.h>

#define F0 512
#define F1 16
#define F2 40

// ---------------- degree / dinv ----------------
__global__ void k_zero(int* deg, int n) {
    int i = blockIdx.x * blockDim.x + threadIdx.x;
    if (i < n) deg[i] = 0;
}

__global__ void k_count(const int* __restrict__ row, int E, int* deg) {
    int e = blockIdx.x * blockDim.x + threadIdx.x;
    if (e < E) atomicAdd(&deg[row[e]], 1);
}

__global__ void k_dinv(const int* __restrict__ deg, float* __restrict__ dinv, int n) {
    int i = blockIdx.x * blockDim.x + threadIdx.x;
    if (i < n) dinv[i] = rsqrtf((float)(deg[i] + 1));  // +1 self loop
}

// ---------------- exclusive scan of deg (3 kernels) ----------------
__global__ void k_scan1(const int* __restrict__ deg, int n, int* __restrict__ excl,
                        int* __restrict__ bsum) {
    __shared__ int lds[256];
    int t = threadIdx.x;
    int i = blockIdx.x * 256 + t;
    int v = (i < n) ? deg[i] : 0;
    lds[t] = v;
    __syncthreads();
    for (int off = 1; off < 256; off <<= 1) {
        int a = (t >= off) ? lds[t - off] : 0;
        __syncthreads();
        lds[t] += a;
        __syncthreads();
    }
    if (i < n) excl[i] = lds[t] - v;
    if (t == 255) bsum[blockIdx.x] = lds[255];
}

__global__ void k_scan2(int* bsum, int B) {
    __shared__ int lds[512];
    int t = threadIdx.x;
    int v = (t < B) ? bsum[t] : 0;
    lds[t] = v;
    __syncthreads();
    for (int off = 1; off < 512; off <<= 1) {
        int a = (t >= off) ? lds[t - off] : 0;
        __syncthreads();
        lds[t] += a;
        __syncthreads();
    }
    if (t < B) bsum[t] = lds[t] - v;  // exclusive block offsets
}

__global__ void k_scan3(int* __restrict__ excl, const int* __restrict__ bsum, int n,
                        int* __restrict__ cursor) {
    int i = blockIdx.x * 256 + threadIdx.x;
    if (i < n) {
        int s = excl[i] + bsum[blockIdx.x];
        excl[i] = s;
        cursor[i] = s;
    }
}

// ---------------- CSR fill (counting sort) ----------------
__global__ void k_fill(const int* __restrict__ row, const int* __restrict__ col, int E,
                       int* cursor, int* __restrict__ colsort) {
    int e = blockIdx.x * blockDim.x + threadIdx.x;
    if (e < E) {
        int p = atomicAdd(&cursor[row[e]], 1);
        colsort[p] = col[e];
    }
}

// ---------------- GEMM1: hp[i][j] = dinv[i] * (x[i,:] @ W1[:,j]) ----------------
// wave-per-node; W1 entirely in registers (lane owns rows 4l..4l+3 and 256+4l..+3)
__global__ __launch_bounds__(256) void k_gemm1(const float* __restrict__ x,
                                               const float* __restrict__ W1,
                                               const float* __restrict__ dinv,
                                               float* __restrict__ hp, int n,
                                               int total_waves) {
    int lane = threadIdx.x & 63;
    int wid = blockIdx.x * (blockDim.x >> 6) + (threadIdx.x >> 6);

    float w[8][16];
#pragma unroll
    for (int h = 0; h < 2; h++) {
#pragma unroll
        for (int r = 0; r < 4; r++) {
            int k = h * 256 + 4 * lane + r;
            const float4* p = (const float4*)(W1 + k * 16);
            float4 a = p[0], b = p[1], c = p[2], d = p[3];
            float* wr = w[h * 4 + r];
            wr[0] = a.x; wr[1] = a.y; wr[2] = a.z; wr[3] = a.w;
            wr[4] = b.x; wr[5] = b.y; wr[6] = b.z; wr[7] = b.w;
            wr[8] = c.x; wr[9] = c.y; wr[10] = c.z; wr[11] = c.w;
            wr[12] = d.x; wr[13] = d.y; wr[14] = d.z; wr[15] = d.w;
        }
    }

    for (int i = wid; i < n; i += total_waves) {
        const float4* xp = (const float4*)(x + (size_t)i * F0);
        float4 xa = xp[lane];       // k = 4*lane .. +3
        float4 xb = xp[64 + lane];  // k = 256+4*lane .. +3
        float acc[16];
#pragma unroll
        for (int j = 0; j < 16; j++) {
            acc[j] = xa.x * w[0][j] + xa.y * w[1][j] + xa.z * w[2][j] + xa.w * w[3][j]
                   + xb.x * w[4][j] + xb.y * w[5][j] + xb.z * w[6][j] + xb.w * w[7][j];
        }
#pragma unroll
        for (int j = 0; j < 16; j++) {
            float v = acc[j];
            v += __shfl_xor(v, 1);
            v += __shfl_xor(v, 2);
            v += __shfl_xor(v, 4);
            v += __shfl_xor(v, 8);
            v += __shfl_xor(v, 16);
            v += __shfl_xor(v, 32);
            acc[j] = v;
        }
        if (lane < 16) {
            float v = acc[0];
#pragma unroll
            for (int j = 1; j < 16; j++) v = (lane == j) ? acc[j] : v;
            hp[(size_t)i * F1 + lane] = dinv[i] * v;
        }
    }
}

// ---------------- SpMM1 + relu + GEMM2: hp2[i][k] = dinv[i]*(h1[i,:] @ W2[:,k]) ----
// block = 16 nodes x 16 features
__global__ __launch_bounds__(256) void k_spmm1(const float* __restrict__ hp,
                                               const int* __restrict__ rs,
                                               const int* __restrict__ deg,
                                               const int* __restrict__ colsort,
                                               const float* __restrict__ dinv,
                                               const float* __restrict__ b1,
                                               const float* __restrict__ W2,
                                               float* __restrict__ hp2, int n) {
    __shared__ float sW2[F1 * F2];
    __shared__ float sh1[16][17];
    int t = threadIdx.x;
    for (int idx = t; idx < F1 * F2; idx += 256) sW2[idx] = W2[idx];

    int jf = t & 15, nl = t >> 4;
    int i = blockIdx.x * 16 + nl;
    float acc = 0.f, di = 0.f;
    if (i < n) {
        di = dinv[i];
        acc = hp[(size_t)i * F1 + jf];  // self loop
        int s = rs[i], c = deg[i];
        for (int e = 0; e < c; e++) {
            int col = colsort[s + e];
            acc += hp[(size_t)col * F1 + jf];
        }
        acc = fmaxf(di * acc + b1[jf], 0.f);
    }
    sh1[nl][jf] = acc;
    __syncthreads();
    if (i < n) {
#pragma unroll
        for (int kk = 0; kk < 3; kk++) {
            int k = jf + kk * 16;
            if (k < F2) {
                float v = 0.f;
#pragma unroll
                for (int j = 0; j < F1; j++) v += sh1[nl][j] * sW2[j * F2 + k];
                hp2[(size_t)i * F2 + k] = di * v;
            }
        }
    }
}

// ---------------- SpMM2 + bias + log_softmax ----------------
// wave-per-node; lanes 0..39 = classes
__global__ __launch_bounds__(256) void k_spmm2(const float* __restrict__ hp2,
                                               const int* __restrict__ rs,
                                               const int* __restrict__ deg,
                                               const int* __restrict__ colsort,
                                               const float* __restrict__ dinv,
                                               const float* __restrict__ b2,
                                               float* __restrict__ out, int n) {
    int lane = threadIdx.x & 63;
    int i = blockIdx.x * 4 + (threadIdx.x >> 6);
    if (i >= n) return;
    bool act = lane < F2;
    float acc = act ? hp2[(size_t)i * F2 + lane] : 0.f;  // self loop
    int s = rs[i], c = deg[i];
    for (int e = 0; e < c; e++) {
        int col = colsort[s + e];
        if (act) acc += hp2[(size_t)col * F2 + lane];
    }
    float val = act ? dinv[i] * acc + b2[lane] : -INFINITY;
    float m = val;
#pragma unroll
    for (int o = 1; o < 64; o <<= 1) m = fmaxf(m, __shfl_xor(m, o));
    float ex = act ? __expf(val - m) : 0.f;
    float ssum = ex;
#pragma unroll
    for (int o = 1; o < 64; o <<= 1) ssum += __shfl_xor(ssum, o);
    if (act) out[(size_t)i * F2 + lane] = val - m - __logf(ssum);
}

extern "C" void kernel_launch(void* const* d_in, const int* in_sizes, int n_in,
                              void* d_out, int out_size, void* d_ws, size_t ws_size,
                              hipStream_t stream) {
    const float* x  = (const float*)d_in[0];
    const float* W1 = (const float*)d_in[1];
    const float* b1 = (const float*)d_in[2];
    const float* W2 = (const float*)d_in[3];
    const float* b2 = (const float*)d_in[4];
    const int*   ei = (const int*)d_in[5];

    int n = in_sizes[0] / F0;
    int E = in_sizes[5] / 2;
    const int* row = ei;
    const int* col = ei + E;

    // workspace carve-up (all 4-byte elements)
    int* deg     = (int*)d_ws;
    int* rs      = deg + n;
    int* cursor  = rs + n;
    int* bsum    = cursor + n;
    int* colsort = bsum + 512;
    float* dinv  = (float*)(colsort + E);
    float* hp    = dinv + n;
    float* hp2   = hp + (size_t)n * F1;

    int B = (n + 255) / 256;

    k_zero<<<(n + 255) / 256, 256, 0, stream>>>(deg, n);
    k_count<<<(E + 255) / 256, 256, 0, stream>>>(row, E, deg);
    k_dinv<<<(n + 255) / 256, 256, 0, stream>>>(deg, dinv, n);
    k_scan1<<<B, 256, 0, stream>>>(deg, n, rs, bsum);
    k_scan2<<<1, 512, 0, stream>>>(bsum, B);
    k_scan3<<<B, 256, 0, stream>>>(rs, bsum, n, cursor);
    k_fill<<<(E + 255) / 256, 256, 0, stream>>>(row, col, E, cursor, colsort);

    int g1_blocks = 768;
    k_gemm1<<<g1_blocks, 256, 0, stream>>>(x, W1, dinv, hp, n, g1_blocks * 4);
    k_spmm1<<<(n + 15) / 16, 256, 0, stream>>>(hp, rs, deg, colsort, dinv, b1, W2, hp2, n);
    k_spmm2<<<(n + 3) / 4, 256, 0, stream>>>(hp2, rs, deg, colsort, dinv, b2,
                                             (float*)d_out, n);
}

// Round 2
// 910.813 us; speedup vs baseline: 1.3078x; 1.3078x over previous
//
#include <hip/hip_runtime.h>
#include <math.h>

#define F0 512
#define F1 16
#define F2 40

// ---------------- degree / dinv ----------------
__global__ void k_zero(int* deg, int n) {
    int i = blockIdx.x * blockDim.x + threadIdx.x;
    if (i < n) deg[i] = 0;
}

__global__ void k_count(const int* __restrict__ row, int E, int* deg) {
    int e = blockIdx.x * blockDim.x + threadIdx.x;
    if (e < E) atomicAdd(&deg[row[e]], 1);
}

__global__ void k_dinv(const int* __restrict__ deg, float* __restrict__ dinv, int n) {
    int i = blockIdx.x * blockDim.x + threadIdx.x;
    if (i < n) dinv[i] = rsqrtf((float)(deg[i] + 1));  // +1 self loop
}

// ---------------- exclusive scan of deg (3 kernels) ----------------
__global__ void k_scan1(const int* __restrict__ deg, int n, int* __restrict__ excl,
                        int* __restrict__ bsum) {
    __shared__ int lds[256];
    int t = threadIdx.x;
    int i = blockIdx.x * 256 + t;
    int v = (i < n) ? deg[i] : 0;
    lds[t] = v;
    __syncthreads();
    for (int off = 1; off < 256; off <<= 1) {
        int a = (t >= off) ? lds[t - off] : 0;
        __syncthreads();
        lds[t] += a;
        __syncthreads();
    }
    if (i < n) excl[i] = lds[t] - v;
    if (t == 255) bsum[blockIdx.x] = lds[255];
}

__global__ void k_scan2(int* bsum, int B) {
    __shared__ int lds[512];
    int t = threadIdx.x;
    int v = (t < B) ? bsum[t] : 0;
    lds[t] = v;
    __syncthreads();
    for (int off = 1; off < 512; off <<= 1) {
        int a = (t >= off) ? lds[t - off] : 0;
        __syncthreads();
        lds[t] += a;
        __syncthreads();
    }
    if (t < B) bsum[t] = lds[t] - v;  // exclusive block offsets
}

__global__ void k_scan3(int* __restrict__ excl, const int* __restrict__ bsum, int n,
                        int* __restrict__ cursor) {
    int i = blockIdx.x * 256 + threadIdx.x;
    if (i < n) {
        int s = excl[i] + bsum[blockIdx.x];
        excl[i] = s;
        cursor[i] = s;
    }
}

// ---------------- CSR fill (counting sort) ----------------
__global__ void k_fill(const int* __restrict__ row, const int* __restrict__ col, int E,
                       int* cursor, int* __restrict__ colsort) {
    int e = blockIdx.x * blockDim.x + threadIdx.x;
    if (e < E) {
        int p = atomicAdd(&cursor[row[e]], 1);
        colsort[p] = col[e];
    }
}

// ---------------- GEMM1: hp[i][j] = dinv[i] * (x[i,:] @ W1[:,j]) ----------------
// wave-per-node; W1 entirely in registers (lane owns rows 4l..4l+3 and 256+4l..+3)
__global__ __launch_bounds__(256) void k_gemm1(const float* __restrict__ x,
                                               const float* __restrict__ W1,
                                               const float* __restrict__ dinv,
                                               float* __restrict__ hp, int n,
                                               int total_waves) {
    int lane = threadIdx.x & 63;
    int wid = blockIdx.x * (blockDim.x >> 6) + (threadIdx.x >> 6);

    float w[8][16];
#pragma unroll
    for (int h = 0; h < 2; h++) {
#pragma unroll
        for (int r = 0; r < 4; r++) {
            int k = h * 256 + 4 * lane + r;
            const float4* p = (const float4*)(W1 + k * 16);
            float4 a = p[0], b = p[1], c = p[2], d = p[3];
            float* wr = w[h * 4 + r];
            wr[0] = a.x; wr[1] = a.y; wr[2] = a.z; wr[3] = a.w;
            wr[4] = b.x; wr[5] = b.y; wr[6] = b.z; wr[7] = b.w;
            wr[8] = c.x; wr[9] = c.y; wr[10] = c.z; wr[11] = c.w;
            wr[12] = d.x; wr[13] = d.y; wr[14] = d.z; wr[15] = d.w;
        }
    }

    for (int i = wid; i < n; i += total_waves) {
        const float4* xp = (const float4*)(x + (size_t)i * F0);
        float4 xa = xp[lane];       // k = 4*lane .. +3
        float4 xb = xp[64 + lane];  // k = 256+4*lane .. +3
        float acc[16];
#pragma unroll
        for (int j = 0; j < 16; j++) {
            acc[j] = xa.x * w[0][j] + xa.y * w[1][j] + xa.z * w[2][j] + xa.w * w[3][j]
                   + xb.x * w[4][j] + xb.y * w[5][j] + xb.z * w[6][j] + xb.w * w[7][j];
        }
#pragma unroll
        for (int j = 0; j < 16; j++) {
            float v = acc[j];
            v += __shfl_xor(v, 1);
            v += __shfl_xor(v, 2);
            v += __shfl_xor(v, 4);
            v += __shfl_xor(v, 8);
            v += __shfl_xor(v, 16);
            v += __shfl_xor(v, 32);
            acc[j] = v;
        }
        if (lane < 16) {
            float v = acc[0];
#pragma unroll
            for (int j = 1; j < 16; j++) v = (lane == j) ? acc[j] : v;
            hp[(size_t)i * F1 + lane] = dinv[i] * v;
        }
    }
}

// ---------------- SpMM1 + relu, store s2 = dinv * h1 (16 feats) ----------------
// wave-per-node: 4 edge-groups x 16 feature-lanes, 2x unroll -> 8 edges in flight
__global__ __launch_bounds__(256) void k_spmm1(const float* __restrict__ hp,
                                               const int* __restrict__ rs,
                                               const int* __restrict__ deg,
                                               const int* __restrict__ colsort,
                                               const float* __restrict__ dinv,
                                               const float* __restrict__ b1,
                                               float* __restrict__ s2, int n) {
    int t = threadIdx.x;
    int lane = t & 63;
    int g = lane >> 4;   // edge group 0..3
    int jf = lane & 15;  // feature
    int i = blockIdx.x * 4 + (t >> 6);
    if (i >= n) return;
    int s = rs[i], c = deg[i];
    float acc = (g == 0) ? hp[(size_t)i * F1 + jf] : 0.f;  // self loop
    int e = g;
    for (; e + 4 < c; e += 8) {
        int c0 = colsort[s + e];
        int c1 = colsort[s + e + 4];
        float v0 = hp[(size_t)c0 * F1 + jf];
        float v1 = hp[(size_t)c1 * F1 + jf];
        acc += v0 + v1;
    }
    if (e < c) acc += hp[(size_t)colsort[s + e] * F1 + jf];
    acc += __shfl_xor(acc, 16);
    acc += __shfl_xor(acc, 32);
    float di = dinv[i];
    float h1 = fmaxf(di * acc + b1[jf], 0.f);
    if (lane < 16) s2[(size_t)i * F1 + jf] = di * h1;  // pre-scale for layer 2
}

// ---------------- SpMM2 (16 feats) + GEMM2 + bias + log_softmax ----------------
__global__ __launch_bounds__(256) void k_spmm2(const float* __restrict__ s2,
                                               const int* __restrict__ rs,
                                               const int* __restrict__ deg,
                                               const int* __restrict__ colsort,
                                               const float* __restrict__ dinv,
                                               const float* __restrict__ W2,
                                               const float* __restrict__ b2,
                                               float* __restrict__ out, int n) {
    __shared__ float sW2[F1 * F2];
    int t = threadIdx.x;
    for (int idx = t; idx < F1 * F2; idx += 256) sW2[idx] = W2[idx];
    __syncthreads();  // before any early return

    int lane = t & 63;
    int g = lane >> 4;
    int jf = lane & 15;
    int i = blockIdx.x * 4 + (t >> 6);
    if (i >= n) return;
    int s = rs[i], c = deg[i];
    float acc = (g == 0) ? s2[(size_t)i * F1 + jf] : 0.f;  // self loop
    int e = g;
    for (; e + 4 < c; e += 8) {
        int c0 = colsort[s + e];
        int c1 = colsort[s + e + 4];
        float v0 = s2[(size_t)c0 * F1 + jf];
        float v1 = s2[(size_t)c1 * F1 + jf];
        acc += v0 + v1;
    }
    if (e < c) acc += s2[(size_t)colsort[s + e] * F1 + jf];
    acc += __shfl_xor(acc, 16);
    acc += __shfl_xor(acc, 32);
    float z = dinv[i] * acc;  // lane l holds z[l & 15]

    // GEMM2 epilogue: lane k (k<40) computes out[k] = sum_j z[j]*W2[j][k] + b2[k]
    bool act = lane < F2;
    int k = act ? lane : 0;
    float o = 0.f;
#pragma unroll
    for (int j = 0; j < F1; j++) {
        float zj = __shfl(z, j);  // lane j holds z[j]
        o += zj * sW2[j * F2 + k];
    }
    float val = act ? o + b2[k] : -INFINITY;
    float m = val;
#pragma unroll
    for (int off = 1; off < 64; off <<= 1) m = fmaxf(m, __shfl_xor(m, off));
    float ex = act ? __expf(val - m) : 0.f;
    float ssum = ex;
#pragma unroll
    for (int off = 1; off < 64; off <<= 1) ssum += __shfl_xor(ssum, off);
    if (act) out[(size_t)i * F2 + lane] = val - m - __logf(ssum);
}

extern "C" void kernel_launch(void* const* d_in, const int* in_sizes, int n_in,
                              void* d_out, int out_size, void* d_ws, size_t ws_size,
                              hipStream_t stream) {
    const float* x  = (const float*)d_in[0];
    const float* W1 = (const float*)d_in[1];
    const float* b1 = (const float*)d_in[2];
    const float* W2 = (const float*)d_in[3];
    const float* b2 = (const float*)d_in[4];
    const int*   ei = (const int*)d_in[5];

    int n = in_sizes[0] / F0;
    int E = in_sizes[5] / 2;
    const int* row = ei;
    const int* col = ei + E;

    // workspace carve-up (all 4-byte elements)
    int* deg     = (int*)d_ws;
    int* rs      = deg + n;
    int* cursor  = rs + n;
    int* bsum    = cursor + n;
    int* colsort = bsum + 512;
    float* dinv  = (float*)(colsort + E);
    float* hp    = dinv + n;                 // n x 16, 64B-aligned rows
    float* s2    = hp + (size_t)n * F1;      // n x 16

    int B = (n + 255) / 256;

    k_zero<<<(n + 255) / 256, 256, 0, stream>>>(deg, n);
    k_count<<<(E + 255) / 256, 256, 0, stream>>>(row, E, deg);
    k_dinv<<<(n + 255) / 256, 256, 0, stream>>>(deg, dinv, n);
    k_scan1<<<B, 256, 0, stream>>>(deg, n, rs, bsum);
    k_scan2<<<1, 512, 0, stream>>>(bsum, B);
    k_scan3<<<B, 256, 0, stream>>>(rs, bsum, n, cursor);
    k_fill<<<(E + 255) / 256, 256, 0, stream>>>(row, col, E, cursor, colsort);

    int g1_blocks = 2048;  // 8192 waves -> ~12 nodes/wave, more BW parallelism
    k_gemm1<<<g1_blocks, 256, 0, stream>>>(x, W1, dinv, hp, n, g1_blocks * 4);
    k_spmm1<<<(n + 3) / 4, 256, 0, stream>>>(hp, rs, deg, colsort, dinv, b1, s2, n);
    k_spmm2<<<(n + 3) / 4, 256, 0, stream>>>(s2, rs, deg, colsort, dinv, W2, b2,
                                             (float*)d_out, n);
}